// Round 13
// baseline (590.453 us; speedup 1.0000x reference)
//
#include <hip/hip_runtime.h>
#include <hip/hip_bf16.h>
#include <stdint.h>

// Castle attention, bf16 MFMA pipeline.
// convert -> qkv GEMM (gld16 dbuf, slab epilogue) -> vcT transpose
//   -> tl (z-merged: one block makes term1(I,K) AND look(K,I))
//   -> castle (2x2-merged 256x256 region; 8 waves = 4 row-panels x 2 col-panels,
//              64x128 per wave; per-wave 128-wide softmax+PV; in-LDS cp merge)
//   -> combine (flash-merge 64-row partials over Kp) -> out GEMM (gld16 dbuf).

typedef unsigned short u16;
typedef __attribute__((ext_vector_type(8))) short s8v;   // 8 x bf16
typedef __attribute__((ext_vector_type(4))) float f4v;   // MFMA accumulator

__device__ __forceinline__ u16 f2bf(float f) {
  union { float f; unsigned u; } v; v.f = f;
  unsigned r = v.u + 0x7FFFu + ((v.u >> 16) & 1u);
  return (u16)(r >> 16);
}
__device__ __forceinline__ float bf2f(u16 u) {
  union { unsigned u; float f; } v; v.u = ((unsigned)u) << 16; return v.f;
}

typedef __attribute__((address_space(1))) const void* gas_t;
typedef __attribute__((address_space(3))) void* las_t;
__device__ __forceinline__ void gld16(const void* g, void* l) {
  __builtin_amdgcn_global_load_lds((gas_t)g, (las_t)l, 16, 0, 0);
}

__device__ __forceinline__ void zero_acc(f4v acc[4][4]) {
  f4v z = {0.f, 0.f, 0.f, 0.f};
#pragma unroll
  for (int m = 0; m < 4; ++m)
#pragma unroll
    for (int n = 0; n < 4; ++n) acc[m][n] = z;
}

// ---------------- converts ----------------

__global__ void convert_x_kernel(const float* __restrict__ in, u16* __restrict__ out) {
  int i = (blockIdx.x * 256 + threadIdx.x) * 4;
  float4 v = *(const float4*)(&in[i]);
  out[i + 0] = f2bf(v.x);
  out[i + 1] = f2bf(v.y);
  out[i + 2] = f2bf(v.z);
  out[i + 3] = f2bf(v.w);
}

__global__ void transpose_convert_kernel(const float* __restrict__ in, u16* __restrict__ out,
                                         int R, int C) {
  __shared__ float tile[32][33];
  int c0 = blockIdx.x * 32, r0 = blockIdx.y * 32;
  for (int rr = threadIdx.y; rr < 32; rr += 8)
    tile[rr][threadIdx.x] = in[(size_t)(r0 + rr) * C + (c0 + threadIdx.x)];
  __syncthreads();
  for (int cc = threadIdx.y; cc < 32; cc += 8)
    out[(size_t)(c0 + cc) * R + (r0 + threadIdx.x)] = f2bf(tile[threadIdx.x][cc]);
}

// ---------------- qkv projection: gld16 dbuf staging + LDS slab epilogue ----------------

__global__ __launch_bounds__(256, 2) void gemm_qkv_kernel(
    const u16* __restrict__ xb, const u16* __restrict__ wqkvT,
    u16* __restrict__ quS, u16* __restrict__ ku, u16* __restrict__ vu,
    u16* __restrict__ qcS, u16* __restrict__ kc, u16* __restrict__ vcN) {
  __shared__ u16 sA[2][8192];
  __shared__ u16 sB[2][8192];
  int bm = blockIdx.x, bn = blockIdx.y;
  int tid = threadIdx.x, lane = tid & 63, w = tid >> 6, wm = w >> 1, wn = w & 1;
  int g = lane >> 4, l15 = lane & 15;
  const int sz = (l15 & 7) << 3;
  const int bo = tid * 16;

  const u16* Ab = xb + (size_t)(bm * 128) * 1024;
  const u16* Bb = wqkvT + (size_t)(bn * 128) * 1024;

  auto stg = [&](const u16* base, int ks, u16* dst) {
#pragma unroll
    for (int it = 0; it < 4; ++it) {
      int o = bo + it * 4096;
      int row = o >> 7, lo = o & 127;
      gld16(base + (size_t)row * 1024 + ks * 64 + ((lo ^ ((row & 7) << 4)) >> 1),
            (char*)dst + o);
    }
  };

  f4v acc[4][4];
  zero_acc(acc);
  stg(Ab, 0, sA[0]);
  stg(Bb, 0, sB[0]);
  stg(Ab, 1, sA[1]);
  stg(Bb, 1, sB[1]);

  for (int ks = 0; ks < 16; ++ks) {
    int buf = ks & 1;
    if (ks < 15)
      asm volatile("s_waitcnt vmcnt(8)" ::: "memory");
    else
      asm volatile("s_waitcnt vmcnt(0)" ::: "memory");
    __builtin_amdgcn_sched_barrier(0);
    __builtin_amdgcn_s_barrier();
    __builtin_amdgcn_sched_barrier(0);
#pragma unroll
    for (int kk = 0; kk < 2; ++kk) {
      int c2 = kk * 32 + g * 8;
      s8v a[4], b[4];
#pragma unroll
      for (int m = 0; m < 4; ++m)
        a[m] = *(const s8v*)(&sA[buf][(wm * 64 + m * 16 + l15) * 64 + (c2 ^ sz)]);
#pragma unroll
      for (int n = 0; n < 4; ++n)
        b[n] = *(const s8v*)(&sB[buf][(wn * 64 + n * 16 + l15) * 64 + (c2 ^ sz)]);
#pragma unroll
      for (int m = 0; m < 4; ++m)
#pragma unroll
        for (int n = 0; n < 4; ++n)
          acc[m][n] = __builtin_amdgcn_mfma_f32_16x16x32_bf16(a[m], b[n], acc[m][n], 0, 0, 0);
    }
    __builtin_amdgcn_s_barrier();
    if (ks + 2 < 16) {
      stg(Ab, ks + 2, sA[buf]);
      stg(Bb, ks + 2, sB[buf]);
    }
  }

  int s = bn >> 3;
  int b = bm >> 4;
  int nn0 = (bm & 15) * 128;
  int hh0 = (bn & 7) * 2;
  float scale = (s == 0 || s == 3) ? 0.125f : 1.f;
  u16* obase;
  switch (s) {
    case 0: obase = quS; break;
    case 1: obase = ku; break;
    case 2: obase = vu; break;
    case 3: obase = qcS; break;
    case 4: obase = kc; break;
    default: obase = vcN; break;
  }
  u16* sE = (u16*)sA;
#pragma unroll
  for (int pass = 0; pass < 2; ++pass) {
    __syncthreads();
    if (wn == pass) {
#pragma unroll
      for (int m = 0; m < 4; ++m)
#pragma unroll
        for (int n = 0; n < 4; ++n)
#pragma unroll
          for (int j = 0; j < 4; ++j) {
            int lrow = wm * 64 + m * 16 + g * 4 + j;
            int d = n * 16 + l15;
            sE[lrow * 64 + d] = f2bf(acc[m][n][j] * scale);
          }
    }
    __syncthreads();
    int bh = (b << 4) + hh0 + pass;
    u16* dst = obase + ((size_t)bh * 2048 + nn0) * 64;
    for (int it = 0; it < 4; ++it) {
      int e = (tid + it * 256) * 8;
      *(uint4*)(dst + e) = *(const uint4*)(&sE[e]);
    }
  }
}

// ------------- vcN [bh][n][d] -> vcT [bh][d][n] -------------

__global__ __launch_bounds__(256) void transpose_v_kernel(const u16* __restrict__ vcN,
                                                          u16* __restrict__ vcT) {
  __shared__ u16 t[64][72];
  int nt = blockIdx.x, bh = blockIdx.y;
  const u16* src = vcN + ((size_t)bh * 2048 + nt * 64) * 64;
  int tid = threadIdx.x;
  for (int i = tid; i < 512; i += 256) {
    int r = i >> 3, cseg = i & 7;
    *(uint4*)(&t[r][cseg * 8]) = *(const uint4*)(src + r * 64 + cseg * 8);
  }
  __syncthreads();
  u16* dst = vcT + (size_t)bh * 64 * 2048 + nt * 64;
  for (int i = tid; i < 512; i += 256) {
    int d = i >> 3, nseg = i & 7;
    u16 tmp[8];
#pragma unroll
    for (int e = 0; e < 8; ++e) tmp[e] = t[nseg * 8 + e][d];
    *(uint4*)(dst + (size_t)d * 2048 + nseg * 8) = *(uint4*)tmp;
  }
}

// ------------- tl (z-merged): block (I,K) -> term1(I,K) AND look(K,I) -------------

__global__ __launch_bounds__(256, 2) void tl_kernel(
    const u16* __restrict__ qcS, const u16* __restrict__ vu,
    const u16* __restrict__ quS, const u16* __restrict__ ku,
    u16* __restrict__ term1p, u16* __restrict__ lookp, int c0) {
  __shared__ u16 S[32768];
  int t = blockIdx.x, lb = blockIdx.y, bh = c0 + lb;
  int I = 0;
  while ((I + 1) * (I + 2) / 2 <= t) ++I;
  int K = t - I * (I + 1) / 2;
  int tid = threadIdx.x, lane = tid & 63, w = tid >> 6, wm = w >> 1, wn = w & 1;
  int g = lane >> 4, l15 = lane & 15;
  const int sz = (l15 & 7) << 3;
  const int bo = tid * 16;

  auto stg = [&](const u16* base, int rt, u16* dst) {
#pragma unroll
    for (int it = 0; it < 4; ++it) {
      int o = bo + it * 4096;
      int row = o >> 7, lo = o & 127;
      gld16(base + ((size_t)bh * 2048 + rt * 128 + row) * 64 + ((lo ^ ((row & 7) << 4)) >> 1),
            (char*)dst + o);
    }
  };
  stg(qcS, I, S);
  stg(vu, K, S + 8192);
  stg(quS, K, S + 16384);
  stg(ku, I, S + 24576);

  asm volatile("s_waitcnt vmcnt(0)" ::: "memory");
  __builtin_amdgcn_sched_barrier(0);
  __syncthreads();

  f4v acc1[4][4], acc2[4][4];
  zero_acc(acc1);
  zero_acc(acc2);
#pragma unroll
  for (int kk = 0; kk < 2; ++kk) {
    int c2 = kk * 32 + g * 8;
    s8v a1[4], b1[4], a2[4], b2[4];
#pragma unroll
    for (int m = 0; m < 4; ++m) {
      a1[m] = *(const s8v*)(&S[(wm * 64 + m * 16 + l15) * 64 + (c2 ^ sz)]);
      a2[m] = *(const s8v*)(&S[16384 + (wm * 64 + m * 16 + l15) * 64 + (c2 ^ sz)]);
    }
#pragma unroll
    for (int n = 0; n < 4; ++n) {
      b1[n] = *(const s8v*)(&S[8192 + (wn * 64 + n * 16 + l15) * 64 + (c2 ^ sz)]);
      b2[n] = *(const s8v*)(&S[24576 + (wn * 64 + n * 16 + l15) * 64 + (c2 ^ sz)]);
    }
#pragma unroll
    for (int m = 0; m < 4; ++m)
#pragma unroll
      for (int n = 0; n < 4; ++n) {
        acc1[m][n] = __builtin_amdgcn_mfma_f32_16x16x32_bf16(a1[m], b1[n], acc1[m][n], 0, 0, 0);
        acc2[m][n] = __builtin_amdgcn_mfma_f32_16x16x32_bf16(a2[m], b2[n], acc2[m][n], 0, 0, 0);
      }
  }
  __syncthreads();

#pragma unroll
  for (int m = 0; m < 4; ++m)
#pragma unroll
    for (int n = 0; n < 4; ++n)
#pragma unroll
      for (int j4 = 0; j4 < 4; ++j4) {
        int lr = wm * 64 + m * 16 + g * 4 + j4;
        int lc = wn * 64 + n * 16 + l15;
        int idx = wn * 8192 + lr * 64 + ((lc & 63) ^ ((lr & 7) << 3));
        float v1 = acc1[m][n][j4];
        v1 = ((K * 128 + lc) > (I * 128 + lr)) ? 0.f : v1;
        S[idx] = f2bf(v1);
        float v2 = acc2[m][n][j4];
        v2 = ((I * 128 + lc) > (K * 128 + lr)) ? (1.f / (1.f + __expf(-v2))) : 0.f;
        S[16384 + idx] = f2bf(v2);
      }
  __syncthreads();

  u16* o1 = term1p + ((size_t)lb * 136 + t) * 16384;
  u16* o2 = lookp + ((size_t)lb * 136 + t) * 16384;
#pragma unroll
  for (int it = 0; it < 8; ++it) {
    int e = (tid + it * 256) * 8;
    *(uint4*)(o1 + e) = *(const uint4*)(&S[e]);
    *(uint4*)(o2 + e) = *(const uint4*)(&S[16384 + e]);
  }
}

// ------------- castle: 256x256 region, 8 waves = 4 row-panels x 2 col-panels -------------
// wave w: rp = w>>1 (64-row panel), cp = w&1 (128-col panel). Per wave: 64x128 scores,
// own 128-wide softmax, own PV over its 128 k. cp pair merges in-LDS -> one 64-row partial.

__global__ __launch_bounds__(512, 1) void castle_kernel(
    const u16* __restrict__ term1p, const u16* __restrict__ lookp,
    const u16* __restrict__ qcS, const u16* __restrict__ kc,
    const u16* __restrict__ vcT, const u16* __restrict__ ztile,
    u16* __restrict__ opart, float* __restrict__ ml, int c0) {
  __shared__ u16 S[65536];  // 128 KB
  int bid = blockIdx.x;
  int lb = bid / 36, sid = bid % 36;
  int bh = c0 + lb;
  int dd = 7, rem = sid;
  while (rem >= 8 - dd) { rem -= 8 - dd; --dd; }
  int Kp = rem, Ip = Kp + dd;

  int tid = threadIdx.x, lane = tid & 63, w = tid >> 6;
  int g = lane >> 4, l15 = lane & 15;
  const int sz = (l15 & 7) << 3;
  int rp = w >> 1, cp = w & 1;
  int i_t = 2 * Ip + (rp >> 1);   // this wave's I tile
  int rowb = (rp & 1) * 64;       // 64-row slice within the tile
  const int bo = tid * 16;

  const char* t1b = (const char*)(term1p + (size_t)lb * 136 * 16384);
  const char* lkb = (const char*)(lookp + (size_t)lb * 136 * 16384);

  f4v su[4][8];
  {
    f4v z = {0.f, 0.f, 0.f, 0.f};
#pragma unroll
    for (int mg = 0; mg < 4; ++mg)
#pragma unroll
      for (int n = 0; n < 8; ++n) su[mg][n] = z;
  }

  auto stage = [&](int h, int buf) {
    int jt = h >> 1, hf = h & 1;
    const char* a0 = (jt <= 2 * Ip)
                         ? t1b + (size_t)(2 * Ip * (2 * Ip + 1) / 2 + jt) * 32768 + hf * 16384
                         : (const char*)ztile;
    const char* a1 = t1b + (size_t)((2 * Ip + 1) * (2 * Ip + 2) / 2 + jt) * 32768 + hf * 16384;
    const char* b0 = lkb + (size_t)(jt * (jt + 1) / 2 + 2 * Kp) * 32768 + hf * 16384;
    const char* b1 = (jt >= 2 * Kp + 1)
                         ? lkb + (size_t)(jt * (jt + 1) / 2 + 2 * Kp + 1) * 32768 + hf * 16384
                         : (const char*)ztile;
    char* dst = (char*)S + buf * 65536;
#pragma unroll
    for (int r = 0; r < 2; ++r) {
      gld16(a0 + bo + r * 8192, dst + bo + r * 8192);
      gld16(a1 + bo + r * 8192, dst + 16384 + bo + r * 8192);
      gld16(b0 + bo + r * 8192, dst + 32768 + bo + r * 8192);
      gld16(b1 + bo + r * 8192, dst + 49152 + bo + r * 8192);
    }
  };

  const int h0 = 4 * Kp, h1 = 4 * Ip + 3;
  stage(h0, 0);
  for (int h = h0; h <= h1; ++h) {
    int cur = (h - h0) & 1;
    if (h < h1) {
      stage(h + 1, cur ^ 1);
      asm volatile("s_waitcnt vmcnt(8)" ::: "memory");
    } else {
      asm volatile("s_waitcnt vmcnt(0)" ::: "memory");
    }
    __builtin_amdgcn_sched_barrier(0);
    __builtin_amdgcn_s_barrier();
    __builtin_amdgcn_sched_barrier(0);
    const u16* TA = S + cur * 32768 + (rp >> 1) * 8192;          // term1 half-tile (this I tile)
    const u16* LB = S + cur * 32768 + 16384 + cp * 8192;         // look half-tile (this col panel)
    __builtin_amdgcn_s_setprio(1);
#pragma unroll
    for (int kk = 0; kk < 2; ++kk) {
      int c2 = kk * 32 + g * 8;
      s8v a[4], b[8];
#pragma unroll
      for (int mg = 0; mg < 4; ++mg)
        a[mg] = *(const s8v*)(&TA[(rowb + mg * 16 + l15) * 64 + (c2 ^ sz)]);
#pragma unroll
      for (int n = 0; n < 8; ++n)
        b[n] = *(const s8v*)(&LB[(n * 16 + l15) * 64 + (c2 ^ sz)]);
#pragma unroll
      for (int mg = 0; mg < 4; ++mg)
#pragma unroll
        for (int n = 0; n < 8; ++n)
          su[mg][n] = __builtin_amdgcn_mfma_f32_16x16x32_bf16(a[mg], b[n], su[mg][n], 0, 0, 0);
    }
    __builtin_amdgcn_s_setprio(0);
    __builtin_amdgcn_s_barrier();
  }

  // qc A-frags for Sc (loaded late to keep j-loop register pressure low)
  s8v qa[4][2];
#pragma unroll
  for (int mg = 0; mg < 4; ++mg)
#pragma unroll
    for (int kk = 0; kk < 2; ++kk)
      qa[mg][kk] = *(const s8v*)(&qcS[((size_t)bh * 2048 + i_t * 128 + rowb + mg * 16 + l15) *
                                          64 + kk * 32 + g * 8]);

  // ---- stage Ks (256x64) at bytes [0,32K) and Vs [kq(4)][64d][64k] at [32K,64K) ----
  {
#pragma unroll
    for (int it = 0; it < 4; ++it) {
      int o = bo + it * 8192;
      int row = o >> 7, lo = o & 127;
      const u16* src = kc + ((size_t)bh * 2048 + Kp * 256 + row) * 64 +
                       ((lo ^ ((row & 7) << 4)) >> 1);
      gld16(src, (char*)S + o);
    }
#pragma unroll
    for (int it = 0; it < 4; ++it) {
      int o = bo + it * 8192;
      int kq = o >> 13, oc = o & 8191;
      int dr = oc >> 7, lo = oc & 127;
      const u16* src = vcT + ((size_t)bh * 64 + dr) * 2048 + Kp * 256 + kq * 64 +
                       ((lo ^ ((dr & 7) << 4)) >> 1);
      gld16(src, (char*)S + 32768 + o);
    }
  }
  // su = -silu(su) while loads fly
#pragma unroll
  for (int mg = 0; mg < 4; ++mg)
#pragma unroll
    for (int n = 0; n < 8; ++n)
#pragma unroll
      for (int j4 = 0; j4 < 4; ++j4) {
        float xv = su[mg][n][j4];
        su[mg][n][j4] = -(xv / (1.f + __expf(-xv)));
      }
  __syncthreads();  // drains vmcnt: Ks/Vs ready

  // ---- Sc accumulate (Ks rows cp*128 + n*16) ----
#pragma unroll
  for (int kk = 0; kk < 2; ++kk) {
    int c = kk * 32 + g * 8;
#pragma unroll
    for (int n = 0; n < 8; ++n) {
      s8v b = *(const s8v*)(&S[(cp * 128 + n * 16 + l15) * 64 + (c ^ sz)]);
#pragma unroll
      for (int mg = 0; mg < 4; ++mg)
        su[mg][n] = __builtin_amdgcn_mfma_f32_16x16x32_bf16(qa[mg][kk], b, su[mg][n], 0, 0, 0);
    }
  }

  // ---- causal mask ----
#pragma unroll
  for (int mg = 0; mg < 4; ++mg)
#pragma unroll
    for (int n = 0; n < 8; ++n)
#pragma unroll
      for (int j4 = 0; j4 < 4; ++j4) {
        int grow = i_t * 128 + rowb + mg * 16 + g * 4 + j4;
        int gcol = Kp * 256 + cp * 128 + n * 16 + l15;
        if (gcol > grow) su[mg][n][j4] = -3.0e38f;
      }

  // ---- per-wave 128-wide softmax ----
  float mrow[4][4], lrow[4][4];
#pragma unroll
  for (int mg = 0; mg < 4; ++mg)
#pragma unroll
    for (int j4 = 0; j4 < 4; ++j4) {
      float v = -3.0e38f;
#pragma unroll
      for (int n = 0; n < 8; ++n) v = fmaxf(v, su[mg][n][j4]);
      v = fmaxf(v, __shfl_xor(v, 1));
      v = fmaxf(v, __shfl_xor(v, 2));
      v = fmaxf(v, __shfl_xor(v, 4));
      v = fmaxf(v, __shfl_xor(v, 8));
      mrow[mg][j4] = v;
      float sum = 0.f;
#pragma unroll
      for (int n = 0; n < 8; ++n) {
        float e = __expf(su[mg][n][j4] - v);
        su[mg][n][j4] = e;
        sum += e;
      }
      sum += __shfl_xor(sum, 1);
      sum += __shfl_xor(sum, 2);
      sum += __shfl_xor(sum, 4);
      sum += __shfl_xor(sum, 8);
      lrow[mg][j4] = sum;
    }

  // ---- PV: wave-private P chunks (64x64), V quarters kq = cp*2 + kq2 ----
  f4v o[4][4];
  zero_acc(o);
  u16* Pw = S + 32768 + w * 4096;  // bytes [65536,131072): 8 waves x 8 KB
#pragma unroll
  for (int kq2 = 0; kq2 < 2; ++kq2) {
    int kq = cp * 2 + kq2;
#pragma unroll
    for (int mg = 0; mg < 4; ++mg)
#pragma unroll
      for (int j4 = 0; j4 < 4; ++j4) {
        int rl = mg * 16 + g * 4 + j4;
        int psz = ((g * 4 + j4) & 7) << 3;
#pragma unroll
        for (int nn = 0; nn < 4; ++nn) {
          int pc = nn * 16 + l15;
          Pw[rl * 64 + (pc ^ psz)] = f2bf(su[mg][kq2 * 4 + nn][j4]);
        }
      }
    asm volatile("s_waitcnt lgkmcnt(0)" ::: "memory");
    __builtin_amdgcn_sched_barrier(0);
#pragma unroll
    for (int kk = 0; kk < 2; ++kk) {
      int c = kk * 32 + g * 8;
      s8v pa[4], vb[4];
#pragma unroll
      for (int mg = 0; mg < 4; ++mg)
        pa[mg] = *(const s8v*)(&Pw[(mg * 16 + l15) * 64 + (c ^ sz)]);
#pragma unroll
      for (int nd = 0; nd < 4; ++nd)
        vb[nd] = *(const s8v*)(&S[16384 + kq * 4096 + (nd * 16 + l15) * 64 + (c ^ sz)]);
#pragma unroll
      for (int mg = 0; mg < 4; ++mg)
#pragma unroll
        for (int nd = 0; nd < 4; ++nd)
          o[mg][nd] = __builtin_amdgcn_mfma_f32_16x16x32_bf16(pa[mg], vb[nd], o[mg][nd], 0, 0, 0);
    }
  }

  // ---- in-LDS cp merge: cp=1 dumps O/m/l; cp=0 rescale-merges, writes partial ----
  __syncthreads();  // everyone done with Ks/Vs/P regions
  if (cp == 1) {
    float* Od = (float*)S + rp * 4096;                  // bytes [0,65536): 4 pairs x 16 KB
    float* Ml = (float*)((char*)S + 65536) + rp * 128;  // m[64] | l[64] per pair
#pragma unroll
    for (int mg = 0; mg < 4; ++mg)
#pragma unroll
      for (int j4 = 0; j4 < 4; ++j4) {
        int row = mg * 16 + g * 4 + j4;
#pragma unroll
        for (int nd = 0; nd < 4; ++nd) Od[row * 64 + nd * 16 + l15] = o[mg][nd][j4];
        if (l15 == 0) {
          Ml[row] = mrow[mg][j4];
          Ml[64 + row] = lrow[mg][j4];
        }
      }
  }
  __syncthreads();
  if (cp == 0) {
    float* Od = (float*)S + rp * 4096;
    float* Ml = (float*)((char*)S + 65536) + rp * 128;
    size_t tb = ((size_t)lb * 32 + i_t * 2 + (rp & 1)) * 8 + Kp;
#pragma unroll
    for (int mg = 0; mg < 4; ++mg)
#pragma unroll
      for (int j4 = 0; j4 < 4; ++j4) {
        int row = mg * 16 + g * 4 + j4;
        float m1 = Ml[row], l1 = Ml[64 + row];
        float m0 = mrow[mg][j4], l0 = lrow[mg][j4];
        float nm = fmaxf(m0, m1);
        float s0 = __expf(m0 - nm), s1 = __expf(m1 - nm);
        if (l15 == 0) {
          ml[tb * 128 + row] = nm;
          ml[tb * 128 + 64 + row] = l0 * s0 + l1 * s1;
        }
#pragma unroll
        for (int nd = 0; nd < 4; ++nd) {
          int dcol = nd * 16 + l15;
          float val = o[mg][nd][j4] * s0 + Od[row * 64 + dcol] * s1;
          opart[(tb * 64 + row) * 64 + dcol] = f2bf(val);
        }
      }
  }
}

// ------------- combine: flash-merge 64-row partials over Kp per (lb, rg) -------------

__global__ __launch_bounds__(256) void combine_kernel(const u16* __restrict__ opart,
                                                      const float* __restrict__ ml,
                                                      u16* __restrict__ attn, int c0) {
  int lb = blockIdx.x, rg = blockIdx.y, bh = c0 + lb;  // rg = i_t*2 + half
  int i_t = rg >> 1;
  int tid = threadIdx.x;
  int row = tid >> 2, dh = (tid & 3) << 4;
  float M = -3.0e38f, L = 0.f;
  float O[16];
#pragma unroll
  for (int i = 0; i < 16; ++i) O[i] = 0.f;
  int np = (i_t >> 1) + 1;
  for (int Kp = 0; Kp < np; ++Kp) {
    size_t tb = ((size_t)lb * 32 + rg) * 8 + Kp;
    float m = ml[tb * 128 + row];
    float l = ml[tb * 128 + 64 + row];
    float nM = fmaxf(M, m);
    float so = __expf(M - nM), sn = __expf(m - nM);
    L = L * so + l * sn;
    const u16* op = opart + (tb * 64 + row) * 64 + dh;
#pragma unroll
    for (int q = 0; q < 2; ++q) {
      s8v ov = *(const s8v*)(op + q * 8);
#pragma unroll
      for (int e = 0; e < 8; ++e)
        O[q * 8 + e] = O[q * 8 + e] * so + bf2f((u16)ov[e]) * sn;
    }
    M = nM;
  }
  float inv = 1.f / L;
  int b = bh >> 4, hh = bh & 15;
  int grow = i_t * 128 + (rg & 1) * 64 + row;
  u16* dst = attn + ((size_t)b * 2048 + grow) * 1024 + hh * 64 + dh;
#pragma unroll
  for (int i = 0; i < 16; ++i) dst[i] = f2bf(O[i] * inv);
}

// ------------- final: out = attn_out @ W_out, f32 (gld16 dbuf) -------------

__global__ __launch_bounds__(256, 2) void gemm_out_kernel(const u16* __restrict__ attn,
                                                          const u16* __restrict__ woutT,
                                                          float* __restrict__ out) {
  __shared__ u16 sA[2][8192];
  __shared__ u16 sB[2][8192];
  int bm = blockIdx.x, bn = blockIdx.y;
  int tid = threadIdx.x, lane = tid & 63, w = tid >> 6, wm = w >> 1, wn = w & 1;
  int g = lane >> 4, l15 = lane & 15;
  const int sz = (l15 & 7) << 3;
  const int bo = tid * 16;

  const u16* Ab = attn + (size_t)(bm * 128) * 1024;
  const u16* Bb = woutT + (size_t)(bn * 128) * 1024;

  auto stg = [&](const u16* base, int ks, u16* dst) {
#pragma unroll
    for (int it = 0; it < 4; ++it) {
      int o = bo + it * 4096;
      int row = o >> 7, lo = o & 127;
      gld16(base + (size_t)row * 1024 + ks * 64 + ((lo ^ ((row & 7) << 4)) >> 1),
            (char*)dst + o);
    }
  };

  f4v acc[4][4];
  zero_acc(acc);
  stg(Ab, 0, sA[0]);
  stg(Bb, 0, sB[0]);
  stg(Ab, 1, sA[1]);
  stg(Bb, 1, sB[1]);

  for (int ks = 0; ks < 16; ++ks) {
    int buf = ks & 1;
    if (ks < 15)
      asm volatile("s_waitcnt vmcnt(8)" ::: "memory");
    else
      asm volatile("s_waitcnt vmcnt(0)" ::: "memory");
    __builtin_amdgcn_sched_barrier(0);
    __builtin_amdgcn_s_barrier();
    __builtin_amdgcn_sched_barrier(0);
#pragma unroll
    for (int kk = 0; kk < 2; ++kk) {
      int c2 = kk * 32 + g * 8;
      s8v a[4], b[4];
#pragma unroll
      for (int m = 0; m < 4; ++m)
        a[m] = *(const s8v*)(&sA[buf][(wm * 64 + m * 16 + l15) * 64 + (c2 ^ sz)]);
#pragma unroll
      for (int n = 0; n < 4; ++n)
        b[n] = *(const s8v*)(&sB[buf][(wn * 64 + n * 16 + l15) * 64 + (c2 ^ sz)]);
#pragma unroll
      for (int m = 0; m < 4; ++m)
#pragma unroll
        for (int n = 0; n < 4; ++n)
          acc[m][n] = __builtin_amdgcn_mfma_f32_16x16x32_bf16(a[m], b[n], acc[m][n], 0, 0, 0);
    }
    __builtin_amdgcn_s_barrier();
    if (ks + 2 < 16) {
      stg(Ab, ks + 2, sA[buf]);
      stg(Bb, ks + 2, sB[buf]);
    }
  }

#pragma unroll
  for (int m = 0; m < 4; ++m)
#pragma unroll
    for (int n = 0; n < 4; ++n)
#pragma unroll
      for (int j = 0; j < 4; ++j) {
        int row = bm * 128 + wm * 64 + m * 16 + g * 4 + j;
        int col = bn * 128 + wn * 64 + n * 16 + l15;
        out[(size_t)row * 1024 + col] = acc[m][n][j];
      }
}

// ---------------- host ----------------

extern "C" void kernel_launch(void* const* d_in, const int* in_sizes, int n_in,
                              void* d_out, int out_size, void* d_ws, size_t ws_size,
                              hipStream_t stream) {
  const float* x = (const float*)d_in[0];
  const float* Wqkv = (const float*)d_in[1];
  const float* Wout = (const float*)d_in[2];
  float* out = (float*)d_out;

  char* base = (char*)d_ws;
  size_t off = 0;
  auto alloc = [&](size_t bytes) -> void* {
    void* p = base + off;
    off += (bytes + 255) & ~(size_t)255;
    return p;
  };

  u16* woutT = (u16*)alloc(1024ull * 1024 * 2);
  u16* quS = (u16*)alloc(32ull * 2048 * 64 * 2);
  u16* ku = (u16*)alloc(32ull * 2048 * 64 * 2);
  u16* vu = (u16*)alloc(32ull * 2048 * 64 * 2);
  u16* qcS = (u16*)alloc(32ull * 2048 * 64 * 2);
  u16* kc = (u16*)alloc(32ull * 2048 * 64 * 2);
  u16* vcN = (u16*)alloc(32ull * 2048 * 64 * 2);
  u16* vcT = (u16*)alloc(32ull * 2048 * 64 * 2);
  u16* attn = (u16*)alloc(4096ull * 1024 * 2);
  u16* ztile = (u16*)alloc(16384);  // 16 KB zero tile for out-of-triangle reads

  size_t perBH = 136ull * 16384 * 2 * 2 + 256ull * 4096 * 2 + 256ull * 128 * 4;
  size_t remain = (ws_size > off) ? (ws_size - off) : 0;
  int chunk = (int)(remain / perBH);
  if (chunk < 1) chunk = 1;
  if (chunk > 32) chunk = 32;
  u16* term1p = (u16*)alloc((size_t)chunk * 136 * 16384 * 2);
  u16* lookp = (u16*)alloc((size_t)chunk * 136 * 16384 * 2);
  u16* opart = (u16*)alloc((size_t)chunk * 256 * 4096 * 2);
  float* mlb = (float*)alloc((size_t)chunk * 256 * 128 * 4);

  u16* xb;
  u16* wqkvT;
  if ((size_t)chunk * 136 * 16384 * 2 >= (4096ull + 6144ull) * 1024 * 2) {
    xb = term1p;
    wqkvT = term1p + 4096ull * 1024;
  } else {
    xb = (u16*)alloc(4096ull * 1024 * 2);
    wqkvT = (u16*)alloc(6144ull * 1024 * 2);
  }

  hipMemsetAsync(ztile, 0, 16384, stream);
  convert_x_kernel<<<4096, 256, 0, stream>>>(x, xb);
  transpose_convert_kernel<<<dim3(192, 32), dim3(32, 8), 0, stream>>>(Wqkv, wqkvT, 1024, 6144);
  transpose_convert_kernel<<<dim3(32, 32), dim3(32, 8), 0, stream>>>(Wout, woutT, 1024, 1024);
  gemm_qkv_kernel<<<dim3(32, 48), 256, 0, stream>>>(xb, wqkvT, quS, ku, vu, qcS, kc, vcN);
  transpose_v_kernel<<<dim3(32, 32), 256, 0, stream>>>(vcN, vcT);

  for (int c0 = 0; c0 < 32; c0 += chunk) {
    int nb = (32 - c0 < chunk) ? (32 - c0) : chunk;
    tl_kernel<<<dim3(136, nb), 256, 0, stream>>>(qcS, vu, quS, ku, term1p, lookp, c0);
    castle_kernel<<<dim3(36 * nb), 512, 0, stream>>>(term1p, lookp, qcS, kc, vcT, ztile,
                                                     opart, mlb, c0);
    combine_kernel<<<dim3(nb, 32), 256, 0, stream>>>(opart, mlb, attn, c0);
  }
  gemm_out_kernel<<<dim3(32, 8), 256, 0, stream>>>(attn, woutT, out);
}

// Round 14
// 491.758 us; speedup vs baseline: 1.2007x; 1.2007x over previous
//
#include <hip/hip_runtime.h>
#include <hip/hip_bf16.h>
#include <stdint.h>

// Castle attention, bf16 MFMA pipeline.
// convert -> qkv GEMM (gld16 dbuf, slab epilogue, writes vcT directly)
//   -> tl (z-merged: one block makes term1(I,K) AND look(K,I))
//   -> castle (2x2-merged: 256x256 score region per block, dbuf j-loop,
//              Su -> -silu -> +Sc -> mask -> 256-wide softmax -> PV partials)
//   -> combine (flash-merge over K-pairs) -> out GEMM (gld16 dbuf).

typedef unsigned short u16;
typedef __attribute__((ext_vector_type(8))) short s8v;   // 8 x bf16
typedef __attribute__((ext_vector_type(4))) float f4v;   // MFMA accumulator

__device__ __forceinline__ u16 f2bf(float f) {
  union { float f; unsigned u; } v; v.f = f;
  unsigned r = v.u + 0x7FFFu + ((v.u >> 16) & 1u);
  return (u16)(r >> 16);
}
__device__ __forceinline__ float bf2f(u16 u) {
  union { unsigned u; float f; } v; v.u = ((unsigned)u) << 16; return v.f;
}

typedef __attribute__((address_space(1))) const void* gas_t;
typedef __attribute__((address_space(3))) void* las_t;
__device__ __forceinline__ void gld16(const void* g, void* l) {
  __builtin_amdgcn_global_load_lds((gas_t)g, (las_t)l, 16, 0, 0);
}

__device__ __forceinline__ void zero_acc(f4v acc[4][4]) {
  f4v z = {0.f, 0.f, 0.f, 0.f};
#pragma unroll
  for (int m = 0; m < 4; ++m)
#pragma unroll
    for (int n = 0; n < 4; ++n) acc[m][n] = z;
}

// ---------------- converts ----------------

__global__ void convert_x_kernel(const float* __restrict__ in, u16* __restrict__ out) {
  int i = (blockIdx.x * 256 + threadIdx.x) * 4;
  float4 v = *(const float4*)(&in[i]);
  out[i + 0] = f2bf(v.x);
  out[i + 1] = f2bf(v.y);
  out[i + 2] = f2bf(v.z);
  out[i + 3] = f2bf(v.w);
}

__global__ void transpose_convert_kernel(const float* __restrict__ in, u16* __restrict__ out,
                                         int R, int C) {
  __shared__ float tile[32][33];
  int c0 = blockIdx.x * 32, r0 = blockIdx.y * 32;
  for (int rr = threadIdx.y; rr < 32; rr += 8)
    tile[rr][threadIdx.x] = in[(size_t)(r0 + rr) * C + (c0 + threadIdx.x)];
  __syncthreads();
  for (int cc = threadIdx.y; cc < 32; cc += 8)
    out[(size_t)(c0 + cc) * R + (r0 + threadIdx.x)] = f2bf(tile[threadIdx.x][cc]);
}

// ---------------- qkv projection: gld16 dbuf staging + LDS slab epilogue ----------------
// s==5 (vc) writes the TRANSPOSED layout vcT[bh][d][n] directly (pitch-72 LDS re-stage).

__global__ __launch_bounds__(256, 2) void gemm_qkv_kernel(
    const u16* __restrict__ xb, const u16* __restrict__ wqkvT,
    u16* __restrict__ quS, u16* __restrict__ ku, u16* __restrict__ vu,
    u16* __restrict__ qcS, u16* __restrict__ kc, u16* __restrict__ vcT) {
  __shared__ u16 sA[2][8192];
  __shared__ u16 sB[2][8192];
  int bm = blockIdx.x, bn = blockIdx.y;
  int tid = threadIdx.x, lane = tid & 63, w = tid >> 6, wm = w >> 1, wn = w & 1;
  int g = lane >> 4, l15 = lane & 15;
  const int sz = (l15 & 7) << 3;
  const int bo = tid * 16;

  const u16* Ab = xb + (size_t)(bm * 128) * 1024;
  const u16* Bb = wqkvT + (size_t)(bn * 128) * 1024;

  auto stg = [&](const u16* base, int ks, u16* dst) {
#pragma unroll
    for (int it = 0; it < 4; ++it) {
      int o = bo + it * 4096;
      int row = o >> 7, lo = o & 127;
      gld16(base + (size_t)row * 1024 + ks * 64 + ((lo ^ ((row & 7) << 4)) >> 1),
            (char*)dst + o);
    }
  };

  f4v acc[4][4];
  zero_acc(acc);
  stg(Ab, 0, sA[0]);
  stg(Bb, 0, sB[0]);
  stg(Ab, 1, sA[1]);
  stg(Bb, 1, sB[1]);

  for (int ks = 0; ks < 16; ++ks) {
    int buf = ks & 1;
    if (ks < 15)
      asm volatile("s_waitcnt vmcnt(8)" ::: "memory");
    else
      asm volatile("s_waitcnt vmcnt(0)" ::: "memory");
    __builtin_amdgcn_sched_barrier(0);
    __builtin_amdgcn_s_barrier();
    __builtin_amdgcn_sched_barrier(0);
#pragma unroll
    for (int kk = 0; kk < 2; ++kk) {
      int c2 = kk * 32 + g * 8;
      s8v a[4], b[4];
#pragma unroll
      for (int m = 0; m < 4; ++m)
        a[m] = *(const s8v*)(&sA[buf][(wm * 64 + m * 16 + l15) * 64 + (c2 ^ sz)]);
#pragma unroll
      for (int n = 0; n < 4; ++n)
        b[n] = *(const s8v*)(&sB[buf][(wn * 64 + n * 16 + l15) * 64 + (c2 ^ sz)]);
#pragma unroll
      for (int m = 0; m < 4; ++m)
#pragma unroll
        for (int n = 0; n < 4; ++n)
          acc[m][n] = __builtin_amdgcn_mfma_f32_16x16x32_bf16(a[m], b[n], acc[m][n], 0, 0, 0);
    }
    __builtin_amdgcn_s_barrier();
    if (ks + 2 < 16) {
      stg(Ab, ks + 2, sA[buf]);
      stg(Bb, ks + 2, sB[buf]);
    }
  }

  int s = bn >> 3;
  int b = bm >> 4;
  int nn0 = (bm & 15) * 128;
  int hh0 = (bn & 7) * 2;
  float scale = (s == 0 || s == 3) ? 0.125f : 1.f;
  u16* sE = (u16*)sA;
  if (s == 5) {
    // vc: write transposed vcT[bh][d][nn0..nn0+127] via pitch-72 LDS slab
#pragma unroll
    for (int pass = 0; pass < 2; ++pass) {
      __syncthreads();
      if (wn == pass) {
#pragma unroll
        for (int m = 0; m < 4; ++m)
#pragma unroll
          for (int n = 0; n < 4; ++n)
#pragma unroll
            for (int j = 0; j < 4; ++j) {
              int lrow = wm * 64 + m * 16 + g * 4 + j;  // n index 0..127
              int d = n * 16 + l15;                     // d index 0..63
              sE[lrow * 72 + d] = f2bf(acc[m][n][j]);
            }
      }
      __syncthreads();
      int bh = (b << 4) + hh0 + pass;
      u16* dst = vcT + (size_t)bh * 64 * 2048 + nn0;
      for (int it = 0; it < 4; ++it) {
        int c2 = tid + it * 256;        // 1024 chunks = 64 d x 16 nsegs
        int dd2 = c2 >> 4, nseg = c2 & 15;
        u16 tmp[8];
#pragma unroll
        for (int e = 0; e < 8; ++e) tmp[e] = sE[(nseg * 8 + e) * 72 + dd2];
        *(uint4*)(dst + (size_t)dd2 * 2048 + nseg * 8) = *(uint4*)tmp;
      }
    }
  } else {
    u16* obase;
    switch (s) {
      case 0: obase = quS; break;
      case 1: obase = ku; break;
      case 2: obase = vu; break;
      case 3: obase = qcS; break;
      default: obase = kc; break;
    }
#pragma unroll
    for (int pass = 0; pass < 2; ++pass) {
      __syncthreads();
      if (wn == pass) {
#pragma unroll
        for (int m = 0; m < 4; ++m)
#pragma unroll
          for (int n = 0; n < 4; ++n)
#pragma unroll
            for (int j = 0; j < 4; ++j) {
              int lrow = wm * 64 + m * 16 + g * 4 + j;
              int d = n * 16 + l15;
              sE[lrow * 64 + d] = f2bf(acc[m][n][j] * scale);
            }
      }
      __syncthreads();
      int bh = (b << 4) + hh0 + pass;
      u16* dst = obase + ((size_t)bh * 2048 + nn0) * 64;
      for (int it = 0; it < 4; ++it) {
        int e = (tid + it * 256) * 8;
        *(uint4*)(dst + e) = *(const uint4*)(&sE[e]);
      }
    }
  }
}

// ------------- tl (z-merged): block (I,K) -> term1(I,K) AND look(K,I) -------------

__global__ __launch_bounds__(256, 2) void tl_kernel(
    const u16* __restrict__ qcS, const u16* __restrict__ vu,
    const u16* __restrict__ quS, const u16* __restrict__ ku,
    u16* __restrict__ term1p, u16* __restrict__ lookp, int c0) {
  __shared__ u16 S[32768];
  int t = blockIdx.x, lb = blockIdx.y, bh = c0 + lb;
  int I = 0;
  while ((I + 1) * (I + 2) / 2 <= t) ++I;
  int K = t - I * (I + 1) / 2;
  int tid = threadIdx.x, lane = tid & 63, w = tid >> 6, wm = w >> 1, wn = w & 1;
  int g = lane >> 4, l15 = lane & 15;
  const int sz = (l15 & 7) << 3;
  const int bo = tid * 16;

  auto stg = [&](const u16* base, int rt, u16* dst) {
#pragma unroll
    for (int it = 0; it < 4; ++it) {
      int o = bo + it * 4096;
      int row = o >> 7, lo = o & 127;
      gld16(base + ((size_t)bh * 2048 + rt * 128 + row) * 64 + ((lo ^ ((row & 7) << 4)) >> 1),
            (char*)dst + o);
    }
  };
  stg(qcS, I, S);
  stg(vu, K, S + 8192);
  stg(quS, K, S + 16384);
  stg(ku, I, S + 24576);

  asm volatile("s_waitcnt vmcnt(0)" ::: "memory");
  __builtin_amdgcn_sched_barrier(0);
  __syncthreads();

  f4v acc1[4][4], acc2[4][4];
  zero_acc(acc1);
  zero_acc(acc2);
#pragma unroll
  for (int kk = 0; kk < 2; ++kk) {
    int c2 = kk * 32 + g * 8;
    s8v a1[4], b1[4], a2[4], b2[4];
#pragma unroll
    for (int m = 0; m < 4; ++m) {
      a1[m] = *(const s8v*)(&S[(wm * 64 + m * 16 + l15) * 64 + (c2 ^ sz)]);
      a2[m] = *(const s8v*)(&S[16384 + (wm * 64 + m * 16 + l15) * 64 + (c2 ^ sz)]);
    }
#pragma unroll
    for (int n = 0; n < 4; ++n) {
      b1[n] = *(const s8v*)(&S[8192 + (wn * 64 + n * 16 + l15) * 64 + (c2 ^ sz)]);
      b2[n] = *(const s8v*)(&S[24576 + (wn * 64 + n * 16 + l15) * 64 + (c2 ^ sz)]);
    }
#pragma unroll
    for (int m = 0; m < 4; ++m)
#pragma unroll
      for (int n = 0; n < 4; ++n) {
        acc1[m][n] = __builtin_amdgcn_mfma_f32_16x16x32_bf16(a1[m], b1[n], acc1[m][n], 0, 0, 0);
        acc2[m][n] = __builtin_amdgcn_mfma_f32_16x16x32_bf16(a2[m], b2[n], acc2[m][n], 0, 0, 0);
      }
  }
  __syncthreads();

#pragma unroll
  for (int m = 0; m < 4; ++m)
#pragma unroll
    for (int n = 0; n < 4; ++n)
#pragma unroll
      for (int j4 = 0; j4 < 4; ++j4) {
        int lr = wm * 64 + m * 16 + g * 4 + j4;
        int lc = wn * 64 + n * 16 + l15;
        int idx = wn * 8192 + lr * 64 + ((lc & 63) ^ ((lr & 7) << 3));
        float v1 = acc1[m][n][j4];
        v1 = ((K * 128 + lc) > (I * 128 + lr)) ? 0.f : v1;
        S[idx] = f2bf(v1);
        float v2 = acc2[m][n][j4];
        v2 = ((I * 128 + lc) > (K * 128 + lr)) ? (1.f / (1.f + __expf(-v2))) : 0.f;
        S[16384 + idx] = f2bf(v2);
      }
  __syncthreads();

  u16* o1 = term1p + ((size_t)lb * 136 + t) * 16384;
  u16* o2 = lookp + ((size_t)lb * 136 + t) * 16384;
#pragma unroll
  for (int it = 0; it < 8; ++it) {
    int e = (tid + it * 256) * 8;
    *(uint4*)(o1 + e) = *(const uint4*)(&S[e]);
    *(uint4*)(o2 + e) = *(const uint4*)(&S[16384 + e]);
  }
}

// ------------- castle (2x2-merged): 256x256 score region per block -------------
// waves: w in [0,8): rhalf = w>>2 (I sub-tile), rsub = w&3 (32-row slice).
// j-loop stages 4 half-tiles (64 KB) per step, dbuf (128 KB LDS).
// Tail: Ks/Vs staged; Sc; unified mask; 256-wide softmax; wave-private P chunks; PV.

__global__ __launch_bounds__(512, 1) void castle_kernel(
    const u16* __restrict__ term1p, const u16* __restrict__ lookp,
    const u16* __restrict__ qcS, const u16* __restrict__ kc,
    const u16* __restrict__ vcT, const u16* __restrict__ ztile,
    u16* __restrict__ opart, float* __restrict__ ml, int c0) {
  __shared__ u16 S[65536];  // 128 KB
  int bid = blockIdx.x;
  int lb = bid / 36, sid = bid % 36;
  int bh = c0 + lb;
  // decode (Ip,Kp) with d = Ip-Kp descending (heaviest first)
  int d = 7, rem = sid;
  while (rem >= 8 - d) { rem -= 8 - d; --d; }
  int Kp = rem, Ip = Kp + d;

  int tid = threadIdx.x, lane = tid & 63, w = tid >> 6;
  int g = lane >> 4, l15 = lane & 15;
  const int sz = (l15 & 7) << 3;
  int rhalf = w >> 2, rsub = w & 3;
  int i_t = 2 * Ip + rhalf;      // this wave's I tile
  int rowbase = rsub * 32;       // row slice within the 128-row tile
  const int bo = tid * 16;       // 512 threads x 16 B = 8 KB per staging round

  const char* t1b = (const char*)(term1p + (size_t)lb * 136 * 16384);
  const char* lkb = (const char*)(lookp + (size_t)lb * 136 * 16384);

  // qc A-frags for Sc (wave's 32 rows of tile i_t)
  s8v qa[2][2];
#pragma unroll
  for (int mg = 0; mg < 2; ++mg)
#pragma unroll
    for (int kk = 0; kk < 2; ++kk)
      qa[mg][kk] = *(const s8v*)(&qcS[((size_t)bh * 2048 + i_t * 128 + rowbase + mg * 16 + l15) *
                                          64 + kk * 32 + g * 8]);

  f4v su[2][16];
  {
    f4v z = {0.f, 0.f, 0.f, 0.f};
#pragma unroll
    for (int mg = 0; mg < 2; ++mg)
#pragma unroll
      for (int n = 0; n < 16; ++n) su[mg][n] = z;
  }

  // stage j-half h into buffer buf: 4 half-tiles, 8 gld16/thread
  auto stage = [&](int h, int buf) {
    int jt = h >> 1, hf = h & 1;
    const char* a0 = (jt <= 2 * Ip)
                         ? t1b + (size_t)(2 * Ip * (2 * Ip + 1) / 2 + jt) * 32768 + hf * 16384
                         : (const char*)ztile;
    const char* a1 = t1b + (size_t)((2 * Ip + 1) * (2 * Ip + 2) / 2 + jt) * 32768 + hf * 16384;
    const char* b0 = lkb + (size_t)(jt * (jt + 1) / 2 + 2 * Kp) * 32768 + hf * 16384;
    const char* b1 = (jt >= 2 * Kp + 1)
                         ? lkb + (size_t)(jt * (jt + 1) / 2 + 2 * Kp + 1) * 32768 + hf * 16384
                         : (const char*)ztile;
    char* dst = (char*)S + buf * 65536;
#pragma unroll
    for (int r = 0; r < 2; ++r) {
      gld16(a0 + bo + r * 8192, dst + bo + r * 8192);
      gld16(a1 + bo + r * 8192, dst + 16384 + bo + r * 8192);
      gld16(b0 + bo + r * 8192, dst + 32768 + bo + r * 8192);
      gld16(b1 + bo + r * 8192, dst + 49152 + bo + r * 8192);
    }
  };

  const int h0 = 4 * Kp, h1 = 4 * Ip + 3;
  stage(h0, 0);
  for (int h = h0; h <= h1; ++h) {
    int cur = (h - h0) & 1;
    if (h < h1) {
      stage(h + 1, cur ^ 1);
      asm volatile("s_waitcnt vmcnt(8)" ::: "memory");
    } else {
      asm volatile("s_waitcnt vmcnt(0)" ::: "memory");
    }
    __builtin_amdgcn_sched_barrier(0);
    __builtin_amdgcn_s_barrier();
    __builtin_amdgcn_sched_barrier(0);
    const u16* TA = S + cur * 32768 + rhalf * 8192;   // this wave's term1 half-tile
    const u16* LB = S + cur * 32768 + 16384;          // both look half-tiles
    __builtin_amdgcn_s_setprio(1);
#pragma unroll
    for (int kk = 0; kk < 2; ++kk) {
      int c2 = kk * 32 + g * 8;
      s8v a[2];
      a[0] = *(const s8v*)(&TA[(rowbase + l15) * 64 + (c2 ^ sz)]);
      a[1] = *(const s8v*)(&TA[(rowbase + 16 + l15) * 64 + (c2 ^ sz)]);
#pragma unroll
      for (int n = 0; n < 16; ++n) {
        s8v b = *(const s8v*)(&LB[(n >> 3) * 8192 + ((n & 7) * 16 + l15) * 64 + (c2 ^ sz)]);
        su[0][n] = __builtin_amdgcn_mfma_f32_16x16x32_bf16(a[0], b, su[0][n], 0, 0, 0);
        su[1][n] = __builtin_amdgcn_mfma_f32_16x16x32_bf16(a[1], b, su[1][n], 0, 0, 0);
      }
    }
    __builtin_amdgcn_s_setprio(0);
    __builtin_amdgcn_s_barrier();
  }

  // ---- stage Ks (256x64) at elems [0,16384) and Vs [kq(4)][64d][64k] at [16384,32768) ----
  {
#pragma unroll
    for (int it = 0; it < 4; ++it) {
      int o = bo + it * 8192;            // [0, 32768) bytes
      int row = o >> 7, lo = o & 127;    // row in [0,256)
      const u16* src = kc + ((size_t)bh * 2048 + Kp * 256 + row) * 64 +
                       ((lo ^ ((row & 7) << 4)) >> 1);
      gld16(src, (char*)S + o);
    }
#pragma unroll
    for (int it = 0; it < 4; ++it) {
      int o = bo + it * 8192;
      int kq = o >> 13, oc = o & 8191;
      int dr = oc >> 7, lo = oc & 127;
      const u16* src = vcT + ((size_t)bh * 64 + dr) * 2048 + Kp * 256 + kq * 64 +
                       ((lo ^ ((dr & 7) << 4)) >> 1);
      gld16(src, (char*)S + 32768 + o);
    }
  }
  // su = -silu(su) while loads fly
#pragma unroll
  for (int mg = 0; mg < 2; ++mg)
#pragma unroll
    for (int n = 0; n < 16; ++n)
#pragma unroll
      for (int j4 = 0; j4 < 4; ++j4) {
        float xv = su[mg][n][j4];
        su[mg][n][j4] = -(xv / (1.f + __expf(-xv)));
      }
  __syncthreads();  // drains vmcnt: Ks/Vs ready

  // ---- Sc accumulate (Ks at elems [0,16384), 256 rows x 64 d) ----
#pragma unroll
  for (int kk = 0; kk < 2; ++kk) {
    int c = kk * 32 + g * 8;
#pragma unroll
    for (int n = 0; n < 16; ++n) {
      s8v b = *(const s8v*)(&S[(n * 16 + l15) * 64 + (c ^ sz)]);
      su[0][n] = __builtin_amdgcn_mfma_f32_16x16x32_bf16(qa[0][kk], b, su[0][n], 0, 0, 0);
      su[1][n] = __builtin_amdgcn_mfma_f32_16x16x32_bf16(qa[1][kk], b, su[1][n], 0, 0, 0);
    }
  }

  // ---- unified causal mask: gcol > grow -> -inf ----
#pragma unroll
  for (int mg = 0; mg < 2; ++mg)
#pragma unroll
    for (int n = 0; n < 16; ++n)
#pragma unroll
      for (int j4 = 0; j4 < 4; ++j4) {
        int grow = i_t * 128 + rowbase + mg * 16 + g * 4 + j4;
        int gcol = Kp * 256 + n * 16 + l15;
        if (gcol > grow) su[mg][n][j4] = -3.0e38f;
      }

  // ---- 256-wide local softmax: m, l per row; su <- exp(su - m) ----
  float mrow[2][4], lrow[2][4];
#pragma unroll
  for (int mg = 0; mg < 2; ++mg)
#pragma unroll
    for (int j4 = 0; j4 < 4; ++j4) {
      float v = -3.0e38f;
#pragma unroll
      for (int n = 0; n < 16; ++n) v = fmaxf(v, su[mg][n][j4]);
      v = fmaxf(v, __shfl_xor(v, 1));
      v = fmaxf(v, __shfl_xor(v, 2));
      v = fmaxf(v, __shfl_xor(v, 4));
      v = fmaxf(v, __shfl_xor(v, 8));
      mrow[mg][j4] = v;
      float sum = 0.f;
#pragma unroll
      for (int n = 0; n < 16; ++n) {
        float e = __expf(su[mg][n][j4] - v);
        su[mg][n][j4] = e;
        sum += e;
      }
      sum += __shfl_xor(sum, 1);
      sum += __shfl_xor(sum, 2);
      sum += __shfl_xor(sum, 4);
      sum += __shfl_xor(sum, 8);
      lrow[mg][j4] = sum;
    }

  // ---- PV via wave-private P chunks: O = P @ Vs, kq in [0,4) ----
  f4v o[2][4];
  {
    f4v z = {0.f, 0.f, 0.f, 0.f};
#pragma unroll
    for (int mg = 0; mg < 2; ++mg)
#pragma unroll
      for (int nd = 0; nd < 4; ++nd) o[mg][nd] = z;
  }
  u16* Pw = S + 32768 + w * 2048;  // wave-private 32x64 chunk (4 KB)
#pragma unroll
  for (int kq = 0; kq < 4; ++kq) {
    // write this wave's P chunk (rows 32, cols 64) swizzled
#pragma unroll
    for (int mg = 0; mg < 2; ++mg)
#pragma unroll
      for (int j4 = 0; j4 < 4; ++j4) {
        int rl = mg * 16 + g * 4 + j4;
        int psz = ((g * 4 + j4) & 7) << 3;
#pragma unroll
        for (int nn = 0; nn < 4; ++nn) {
          int pc = nn * 16 + l15;
          Pw[rl * 64 + (pc ^ psz)] = f2bf(su[mg][kq * 4 + nn][j4]);
        }
      }
    asm volatile("s_waitcnt lgkmcnt(0)" ::: "memory");
    __builtin_amdgcn_sched_barrier(0);
#pragma unroll
    for (int kk = 0; kk < 2; ++kk) {
      int c = kk * 32 + g * 8;
      s8v pa[2], vb[4];
      pa[0] = *(const s8v*)(&Pw[(l15) * 64 + (c ^ sz)]);
      pa[1] = *(const s8v*)(&Pw[(16 + l15) * 64 + (c ^ sz)]);
#pragma unroll
      for (int nd = 0; nd < 4; ++nd)
        vb[nd] = *(const s8v*)(&S[16384 + kq * 4096 + (nd * 16 + l15) * 64 + (c ^ sz)]);
#pragma unroll
      for (int mg = 0; mg < 2; ++mg)
#pragma unroll
        for (int nd = 0; nd < 4; ++nd)
          o[mg][nd] = __builtin_amdgcn_mfma_f32_16x16x32_bf16(pa[mg], vb[nd], o[mg][nd], 0, 0, 0);
    }
  }

  // ---- write partials: pidx = i_t*8 + Kp ----
  size_t tb = (size_t)lb * 128 + i_t * 8 + Kp;
#pragma unroll
  for (int mg = 0; mg < 2; ++mg)
#pragma unroll
    for (int nd = 0; nd < 4; ++nd)
#pragma unroll
      for (int j4 = 0; j4 < 4; ++j4) {
        int prow = rowbase + mg * 16 + g * 4 + j4;
        int dcol = nd * 16 + l15;
        opart[(tb * 128 + prow) * 64 + dcol] = f2bf(o[mg][nd][j4]);
      }
  if (l15 == 0) {
#pragma unroll
    for (int mg = 0; mg < 2; ++mg)
#pragma unroll
      for (int j4 = 0; j4 < 4; ++j4) {
        int prow = rowbase + mg * 16 + g * 4 + j4;
        ml[tb * 256 + prow] = mrow[mg][j4];
        ml[tb * 256 + 128 + prow] = lrow[mg][j4];
      }
  }
}

// ------------- combine: flash-merge the <=8 K-pair partials per (I, head) -------------

__global__ __launch_bounds__(256) void combine_kernel(const u16* __restrict__ opart,
                                                      const float* __restrict__ ml,
                                                      u16* __restrict__ attn, int c0) {
  int lb = blockIdx.x, I = blockIdx.y, bh = c0 + lb;
  int tid = threadIdx.x;
  int row = tid >> 1, dh = (tid & 1) << 5;
  float M = -3.0e38f, L = 0.f;
  float O[32];
#pragma unroll
  for (int i = 0; i < 32; ++i) O[i] = 0.f;
  int kmax = I >> 1;
  for (int K = 0; K <= kmax; ++K) {
    size_t tb = (size_t)lb * 128 + I * 8 + K;
    float m = ml[tb * 256 + row];
    float l = ml[tb * 256 + 128 + row];
    float newM = fmaxf(M, m);
    float so = __expf(M - newM), sn = __expf(m - newM);
    L = L * so + l * sn;
    const u16* op = opart + (tb * 128 + row) * 64 + dh;
#pragma unroll
    for (int q = 0; q < 4; ++q) {
      s8v ov = *(const s8v*)(op + q * 8);
#pragma unroll
      for (int e = 0; e < 8; ++e)
        O[q * 8 + e] = O[q * 8 + e] * so + bf2f((u16)ov[e]) * sn;
    }
    M = newM;
  }
  float inv = 1.f / L;
  int b = bh >> 4, hh = bh & 15;
  u16* dst = attn + ((size_t)b * 2048 + I * 128 + row) * 1024 + hh * 64 + dh;
#pragma unroll
  for (int i = 0; i < 32; ++i) dst[i] = f2bf(O[i] * inv);
}

// ------------- final: out = attn_out @ W_out, f32 (gld16 dbuf) -------------

__global__ __launch_bounds__(256, 2) void gemm_out_kernel(const u16* __restrict__ attn,
                                                          const u16* __restrict__ woutT,
                                                          float* __restrict__ out) {
  __shared__ u16 sA[2][8192];
  __shared__ u16 sB[2][8192];
  int bm = blockIdx.x, bn = blockIdx.y;
  int tid = threadIdx.x, lane = tid & 63, w = tid >> 6, wm = w >> 1, wn = w & 1;
  int g = lane >> 4, l15 = lane & 15;
  const int sz = (l15 & 7) << 3;
  const int bo = tid * 16;

  const u16* Ab = attn + (size_t)(bm * 128) * 1024;
  const u16* Bb = woutT + (size_t)(bn * 128) * 1024;

  auto stg = [&](const u16* base, int ks, u16* dst) {
#pragma unroll
    for (int it = 0; it < 4; ++it) {
      int o = bo + it * 4096;
      int row = o >> 7, lo = o & 127;
      gld16(base + (size_t)row * 1024 + ks * 64 + ((lo ^ ((row & 7) << 4)) >> 1),
            (char*)dst + o);
    }
  };

  f4v acc[4][4];
  zero_acc(acc);
  stg(Ab, 0, sA[0]);
  stg(Bb, 0, sB[0]);
  stg(Ab, 1, sA[1]);
  stg(Bb, 1, sB[1]);

  for (int ks = 0; ks < 16; ++ks) {
    int buf = ks & 1;
    if (ks < 15)
      asm volatile("s_waitcnt vmcnt(8)" ::: "memory");
    else
      asm volatile("s_waitcnt vmcnt(0)" ::: "memory");
    __builtin_amdgcn_sched_barrier(0);
    __builtin_amdgcn_s_barrier();
    __builtin_amdgcn_sched_barrier(0);
#pragma unroll
    for (int kk = 0; kk < 2; ++kk) {
      int c2 = kk * 32 + g * 8;
      s8v a[4], b[4];
#pragma unroll
      for (int m = 0; m < 4; ++m)
        a[m] = *(const s8v*)(&sA[buf][(wm * 64 + m * 16 + l15) * 64 + (c2 ^ sz)]);
#pragma unroll
      for (int n = 0; n < 4; ++n)
        b[n] = *(const s8v*)(&sB[buf][(wn * 64 + n * 16 + l15) * 64 + (c2 ^ sz)]);
#pragma unroll
      for (int m = 0; m < 4; ++m)
#pragma unroll
        for (int n = 0; n < 4; ++n)
          acc[m][n] = __builtin_amdgcn_mfma_f32_16x16x32_bf16(a[m], b[n], acc[m][n], 0, 0, 0);
    }
    __builtin_amdgcn_s_barrier();
    if (ks + 2 < 16) {
      stg(Ab, ks + 2, sA[buf]);
      stg(Bb, ks + 2, sB[buf]);
    }
  }

#pragma unroll
  for (int m = 0; m < 4; ++m)
#pragma unroll
    for (int n = 0; n < 4; ++n)
#pragma unroll
      for (int j = 0; j < 4; ++j) {
        int row = bm * 128 + wm * 64 + m * 16 + g * 4 + j;
        int col = bn * 128 + wn * 64 + n * 16 + l15;
        out[(size_t)row * 1024 + col] = acc[m][n][j];
      }
}

// ---------------- host ----------------

extern "C" void kernel_launch(void* const* d_in, const int* in_sizes, int n_in,
                              void* d_out, int out_size, void* d_ws, size_t ws_size,
                              hipStream_t stream) {
  const float* x = (const float*)d_in[0];
  const float* Wqkv = (const float*)d_in[1];
  const float* Wout = (const float*)d_in[2];
  float* out = (float*)d_out;

  char* base = (char*)d_ws;
  size_t off = 0;
  auto alloc = [&](size_t bytes) -> void* {
    void* p = base + off;
    off += (bytes + 255) & ~(size_t)255;
    return p;
  };

  u16* woutT = (u16*)alloc(1024ull * 1024 * 2);
  u16* quS = (u16*)alloc(32ull * 2048 * 64 * 2);
  u16* ku = (u16*)alloc(32ull * 2048 * 64 * 2);
  u16* vu = (u16*)alloc(32ull * 2048 * 64 * 2);
  u16* qcS = (u16*)alloc(32ull * 2048 * 64 * 2);
  u16* kc = (u16*)alloc(32ull * 2048 * 64 * 2);
  u16* vcT = (u16*)alloc(32ull * 2048 * 64 * 2);
  u16* attn = (u16*)alloc(4096ull * 1024 * 2);
  u16* ztile = (u16*)alloc(16384);  // 16 KB zero tile for out-of-triangle reads

  size_t perBH = 136ull * 16384 * 2 * 2 + 128ull * 128 * 64 * 2 + 128ull * 256 * 4;
  size_t remain = (ws_size > off) ? (ws_size - off) : 0;
  int chunk = (int)(remain / perBH);
  if (chunk < 1) chunk = 1;
  if (chunk > 32) chunk = 32;
  u16* term1p = (u16*)alloc((size_t)chunk * 136 * 16384 * 2);
  u16* lookp = (u16*)alloc((size_t)chunk * 136 * 16384 * 2);
  u16* opart = (u16*)alloc((size_t)chunk * 128 * 8192 * 2);
  float* mlb = (float*)alloc((size_t)chunk * 128 * 256 * 4);

  u16* xb;
  u16* wqkvT;
  if ((size_t)chunk * 136 * 16384 * 2 >= (4096ull + 6144ull) * 1024 * 2) {
    xb = term1p;
    wqkvT = term1p + 4096ull * 1024;
  } else {
    xb = (u16*)alloc(4096ull * 1024 * 2);
    wqkvT = (u16*)alloc(6144ull * 1024 * 2);
  }

  hipMemsetAsync(ztile, 0, 16384, stream);
  convert_x_kernel<<<4096, 256, 0, stream>>>(x, xb);
  transpose_convert_kernel<<<dim3(192, 32), dim3(32, 8), 0, stream>>>(Wqkv, wqkvT, 1024, 6144);
  transpose_convert_kernel<<<dim3(32, 32), dim3(32, 8), 0, stream>>>(Wout, woutT, 1024, 1024);
  gemm_qkv_kernel<<<dim3(32, 48), 256, 0, stream>>>(xb, wqkvT, quS, ku, vu, qcS, kc, vcT);

  for (int c0 = 0; c0 < 32; c0 += chunk) {
    int nb = (32 - c0 < chunk) ? (32 - c0) : chunk;
    tl_kernel<<<dim3(136, nb), 256, 0, stream>>>(qcS, vu, quS, ku, term1p, lookp, c0);
    castle_kernel<<<dim3(36 * nb), 512, 0, stream>>>(term1p, lookp, qcS, kc, vcT, ztile,
                                                     opart, mlb, c0);
    combine_kernel<<<dim3(nb, 16), 256, 0, stream>>>(opart, mlb, attn, c0);
  }
  gemm_out_kernel<<<dim3(32, 8), 256, 0, stream>>>(attn, woutT, out);
}